// Round 9
// baseline (261.613 us; speedup 1.0000x reference)
//
#include <hip/hip_runtime.h>
#include <cstdint>
#include <cstddef>

// B=8, N=2048, C=512
// out = feature + softmax(Q K^T) @ V / sqrt(C),  Q = X Wq^T + bq etc.
// R9: all GEMMs switched 16x16x32 -> 32x32x16 MFMA (half the MFMA instrs,
//     ~17% fewer MFMA cycles, same ds_read traffic, same acc regs) to cut
//     the VALU/issue pressure that R8 showed (VALUBusy 43% vs MfmaUtil 21%).
//     Structure otherwise R8: 2048-block QK (1 n-tile/block — cross-block TLP
//     proven R7/R8), Vt-folded QKV, 2-n-tile PV, BK=64 XOR-swizzled LDS
//     (0 bank conflicts proven R6).

typedef __bf16 bf16x8 __attribute__((ext_vector_type(8)));
typedef float f32x16 __attribute__((ext_vector_type(16)));
typedef short short4v __attribute__((ext_vector_type(4)));
typedef short short8v __attribute__((ext_vector_type(8)));

__device__ __forceinline__ short f2b(float f) {
  union { float f; unsigned u; } u; u.f = f;
  unsigned r = (u.u + 0x7fffu + ((u.u >> 16) & 1u)) >> 16;  // RNE
  return (short)r;
}

#define GLDS(gptr, lptr) \
  __builtin_amdgcn_global_load_lds( \
      (const __attribute__((address_space(1))) unsigned int*)(const void*)(gptr), \
      (__attribute__((address_space(3))) unsigned int*)(void*)(lptr), 16, 0, 0)

// fragment load from a row-major [rows][64] LDS buffer with XOR-swizzled
// 8-short chunks. kq = kstep*2 + (lane>>5).
__device__ __forceinline__ bf16x8 ldfrag64(const short* buf, int row, int kq) {
  return *(const bf16x8*)(buf + row * 64 + ((kq ^ (row & 7)) * 8));
}

// ---------------- merged prep: feature->bf16, weights->bf16, bias pack, l=0 ----------------
__global__ __launch_bounds__(256) void prep(const float* __restrict__ f,
                                            const float* __restrict__ w0,
                                            const float* __restrict__ w1,
                                            const float* __restrict__ w2,
                                            const float* __restrict__ b0,
                                            const float* __restrict__ b1,
                                            const float* __restrict__ b2,
                                            short* __restrict__ Xb, short* __restrict__ Wb,
                                            float* __restrict__ biasP, float* __restrict__ l) {
  const int bid = blockIdx.x;
  const int t = threadIdx.x;
  if (bid < 8192) {                       // feature: 2097152 float4
    int i = bid * 256 + t;
    float4 v = ((const float4*)f)[i];
    short4v o = { f2b(v.x), f2b(v.y), f2b(v.z), f2b(v.w) };
    *(short4v*)(Xb + (size_t)i * 4) = o;
  } else if (bid < 8960) {                // weights: 196608 float4
    int i = (bid - 8192) * 256 + t;
    const float* src = (i < 65536) ? w0 : (i < 131072) ? w1 : w2;
    float4 v = ((const float4*)src)[i & 65535];
    short4v o = { f2b(v.x), f2b(v.y), f2b(v.z), f2b(v.w) };
    *(short4v*)(Wb + (size_t)i * 4) = o;
  } else {                                // 8 blocks: l zero (16384 f32) + bias (1536)
    int i = (bid - 8960) * 256 + t;       // 0..2047
    float4 z = { 0.f, 0.f, 0.f, 0.f };
    ((float4*)l)[i * 2] = z;
    ((float4*)l)[i * 2 + 1] = z;
    if (i < 1536) {
      const float* s = (i < 512) ? b0 : (i < 1024) ? b1 : b2;
      biasP[i] = s[i & 511];
    }
  }
}

// ---------------- fused QKV projection: 128x128 tile, BK=64 swizzled, 32x32x16 ----------------
// z<2 (Q,K): A-op = W rows -> n-contiguous quads -> store [m][n].
// z==2 (V):  A-op = X rows -> m-contiguous quads -> store Vt[d][m] directly.
__global__ __launch_bounds__(256) void gemm_qkv(const short* __restrict__ X,
                                                const short* __restrict__ Wall,
                                                const float* __restrict__ biasP,
                                                short* __restrict__ Out,
                                                short* __restrict__ VtOut) {
  __shared__ __align__(16) short Xs[128 * 64];
  __shared__ __align__(16) short Ws[128 * 64];
  const int z = blockIdx.z;
  const short* Wm = Wall + (size_t)z * 262144;
  const int m0 = blockIdx.y * 128, n0 = blockIdx.x * 128;
  const int t = threadIdx.x;
  const int lane = t & 63, w = t >> 6;
  const int wn = (w & 1) * 64, wm = (w >> 1) * 64;
  const int c31 = lane & 31, l5 = lane >> 5;

  f32x16 acc[2][2] = {};  // z<2: [i over n][j over m]; z==2: [i over m][j over d]

  for (int k0 = 0; k0 < 512; k0 += 64) {
    __syncthreads();
#pragma unroll
    for (int u = 0; u < 4; ++u) {
      int cc = t + u * 256;
      int r = cc >> 3, cs = cc & 7;
      int kk = ((cs ^ (r & 7)) * 8);
      GLDS(X + (size_t)(m0 + r) * 512 + k0 + kk, Xs + cc * 8);
      GLDS(Wm + (size_t)(n0 + r) * 512 + k0 + kk, Ws + cc * 8);
    }
    __syncthreads();
#pragma unroll
    for (int ks = 0; ks < 4; ++ks) {
      const int kq = ks * 2 + l5;
      bf16x8 wf[2], xf[2];
#pragma unroll
      for (int i = 0; i < 2; ++i) wf[i] = ldfrag64(Ws, wn + i * 32 + c31, kq);
#pragma unroll
      for (int j = 0; j < 2; ++j) xf[j] = ldfrag64(Xs, wm + j * 32 + c31, kq);
      if (z < 2) {
#pragma unroll
        for (int i = 0; i < 2; ++i)
#pragma unroll
          for (int j = 0; j < 2; ++j)
            acc[i][j] = __builtin_amdgcn_mfma_f32_32x32x16_bf16(wf[i], xf[j], acc[i][j], 0, 0, 0);
      } else {
#pragma unroll
        for (int i = 0; i < 2; ++i)
#pragma unroll
          for (int j = 0; j < 2; ++j)
            acc[i][j] = __builtin_amdgcn_mfma_f32_32x32x16_bf16(xf[i], wf[j], acc[i][j], 0, 0, 0);
      }
    }
  }

  // C/D: col = lane&31 (B-side), row = (reg&3)+8*(reg>>2)+4*(lane>>5) (A-side)
  if (z < 2) {
#pragma unroll
    for (int i = 0; i < 2; ++i)
#pragma unroll
      for (int q = 0; q < 4; ++q) {
        int nb = n0 + wn + i * 32 + q * 8 + l5 * 4;
        float4 bs = *(const float4*)(biasP + z * 512 + nb);
#pragma unroll
        for (int j = 0; j < 2; ++j) {
          int m = m0 + wm + j * 32 + c31;
          short4v o = { f2b(acc[i][j][q * 4 + 0] + bs.x), f2b(acc[i][j][q * 4 + 1] + bs.y),
                        f2b(acc[i][j][q * 4 + 2] + bs.z), f2b(acc[i][j][q * 4 + 3] + bs.w) };
          *(short4v*)(Out + (size_t)z * 8388608 + (size_t)m * 512 + nb) = o;
        }
      }
  } else {
    const int zB = blockIdx.y >> 4;          // 128-row tiles, 16 per batch
    const int mb = m0 & 2047;
#pragma unroll
    for (int i = 0; i < 2; ++i)
#pragma unroll
      for (int q = 0; q < 4; ++q) {
        int mloc = mb + wm + i * 32 + q * 8 + l5 * 4;
#pragma unroll
        for (int j = 0; j < 2; ++j) {
          int d = n0 + wn + j * 32 + c31;
          float bd = biasP[1024 + d];
          short4v o = { f2b(acc[i][j][q * 4 + 0] + bd), f2b(acc[i][j][q * 4 + 1] + bd),
                        f2b(acc[i][j][q * 4 + 2] + bd), f2b(acc[i][j][q * 4 + 3] + bd) };
          *(short4v*)(VtOut + (size_t)zB * 1048576 + (size_t)d * 2048 + mloc) = o;
        }
      }
  }
}

// ---------------- QK^T: 128x128 tile, BK=64 swizzled, 32x32x16, exp epilogue ----------------
// grid (16, 16, 8) = 2048 blocks. A-op = K rows (key quad-contig), B-op = Q rows.
__global__ __launch_bounds__(256) void gemm_qk(const short* __restrict__ Q,
                                               const short* __restrict__ Kb,
                                               short* __restrict__ P,
                                               float* __restrict__ l) {
  __shared__ __align__(16) short Qs[128 * 64];
  __shared__ __align__(16) short Ks[128 * 64];
  const int z = blockIdx.z;
  const short* A = Q + (size_t)z * 2048 * 512;
  const short* Bm = Kb + (size_t)z * 2048 * 512;
  const int m0 = blockIdx.y * 128, n0 = blockIdx.x * 128;
  const int t = threadIdx.x;
  const int lane = t & 63, w = t >> 6;
  const int wn = (w & 1) * 64, wm = (w >> 1) * 64;
  const int c31 = lane & 31, l5 = lane >> 5;

  f32x16 acc[2][2] = {};  // [i over keys][j over queries]

  for (int k0 = 0; k0 < 512; k0 += 64) {
    __syncthreads();
#pragma unroll
    for (int u = 0; u < 4; ++u) {
      int cc = t + u * 256;
      int r = cc >> 3, cs = cc & 7;
      int kk = ((cs ^ (r & 7)) * 8);
      GLDS(A + (size_t)(m0 + r) * 512 + k0 + kk, Qs + cc * 8);
      GLDS(Bm + (size_t)(n0 + r) * 512 + k0 + kk, Ks + cc * 8);
    }
    __syncthreads();
#pragma unroll
    for (int ks = 0; ks < 4; ++ks) {
      const int kq = ks * 2 + l5;
      bf16x8 kf[2], qf[2];
#pragma unroll
      for (int i = 0; i < 2; ++i) kf[i] = ldfrag64(Ks, wn + i * 32 + c31, kq);
#pragma unroll
      for (int j = 0; j < 2; ++j) qf[j] = ldfrag64(Qs, wm + j * 32 + c31, kq);
#pragma unroll
      for (int i = 0; i < 2; ++i)
#pragma unroll
        for (int j = 0; j < 2; ++j)
          acc[i][j] = __builtin_amdgcn_mfma_f32_32x32x16_bf16(kf[i], qf[j], acc[i][j], 0, 0, 0);
    }
  }

  float rs[2] = { 0.f, 0.f };  // per query-subtile row sums (this lane's query col)
#pragma unroll
  for (int i = 0; i < 2; ++i)
#pragma unroll
    for (int q = 0; q < 4; ++q) {
      int nb = n0 + wn + i * 32 + q * 8 + l5 * 4;
#pragma unroll
      for (int j = 0; j < 2; ++j) {
        int m = m0 + wm + j * 32 + c31;
        short4v o;
        float part = 0.f;
#pragma unroll
        for (int r = 0; r < 4; ++r) {
          float e = exp2f(acc[i][j][q * 4 + r] * 1.4426950408889634f);
          o[r] = f2b(e);
          part += e;
        }
        *(short4v*)(P + (size_t)z * 4194304 + (size_t)m * 2048 + nb) = o;
        rs[j] += part;
      }
    }
  // lanes l and l^32 cover complementary key rows for the same query col
#pragma unroll
  for (int j = 0; j < 2; ++j) rs[j] += __shfl_xor(rs[j], 32);
  if (lane < 32) {
#pragma unroll
    for (int j = 0; j < 2; ++j)
      atomicAdd(&l[z * 2048 + m0 + wm + j * 32 + lane], rs[j]);
  }
}

// ---------------- PV: 64x256 per block (2 n-tiles share Ps), BK=64 swizzled, 32x32x16 ----------------
// grid (2, 32, 8). A-op = Vt rows (d quad-contig), B-op = P rows.
__global__ __launch_bounds__(256) void gemm_pv(const short* __restrict__ Pm,
                                               const short* __restrict__ Vt,
                                               const float* __restrict__ l,
                                               const float* __restrict__ resid,
                                               float* __restrict__ out, float scale) {
  __shared__ __align__(16) short Ps[64 * 64];        // 8 KB
  __shared__ __align__(16) short Vs[2][128 * 64];    // 32 KB
  const int z = blockIdx.z;
  const short* A = Pm + (size_t)z * 4194304;   // [2048][2048]
  const short* Bm = Vt + (size_t)z * 1048576;  // [512][2048]
  const int m0 = blockIdx.y * 64, n0 = blockIdx.x * 256;
  const int t = threadIdx.x;
  const int lane = t & 63, w = t >> 6;
  const int wn = (w & 1) * 64, wm = (w >> 1) * 32;
  const int c31 = lane & 31, l5 = lane >> 5;

  f32x16 acc[2][2] = {};  // [nt][i over d]; queries = wave's 32-row group

  for (int k0 = 0; k0 < 2048; k0 += 64) {
    __syncthreads();
#pragma unroll
    for (int u = 0; u < 2; ++u) {        // Ps: 512 chunks
      int cc = t + u * 256;
      int r = cc >> 3, cs = cc & 7;
      int kk = ((cs ^ (r & 7)) * 8);
      GLDS(A + (size_t)(m0 + r) * 2048 + k0 + kk, Ps + cc * 8);
    }
#pragma unroll
    for (int nt = 0; nt < 2; ++nt)
#pragma unroll
      for (int u = 0; u < 4; ++u) {      // Vs[nt]: 1024 chunks
        int cc = t + u * 256;
        int r = cc >> 3, cs = cc & 7;
        int kk = ((cs ^ (r & 7)) * 8);
        GLDS(Bm + (size_t)(n0 + nt * 128 + r) * 2048 + k0 + kk, Vs[nt] + cc * 8);
      }
    __syncthreads();
#pragma unroll
    for (int ks = 0; ks < 4; ++ks) {
      const int kq = ks * 2 + l5;
      bf16x8 pf = ldfrag64(Ps, wm + c31, kq);
#pragma unroll
      for (int nt = 0; nt < 2; ++nt)
#pragma unroll
        for (int i = 0; i < 2; ++i) {
          bf16x8 vf = ldfrag64(Vs[nt], wn + i * 32 + c31, kq);
          acc[nt][i] = __builtin_amdgcn_mfma_f32_32x32x16_bf16(vf, pf, acc[nt][i], 0, 0, 0);
        }
    }
  }

  const int m = m0 + wm + c31;
  const float linv = scale / l[z * 2048 + m];
#pragma unroll
  for (int nt = 0; nt < 2; ++nt)
#pragma unroll
    for (int i = 0; i < 2; ++i)
#pragma unroll
      for (int q = 0; q < 4; ++q) {
        int d = n0 + nt * 128 + wn + i * 32 + q * 8 + l5 * 4;
        size_t idx = (size_t)z * 1048576 + (size_t)m * 512 + d;
        float4 rv = *(const float4*)(resid + idx);
        float4 o = { rv.x + acc[nt][i][q * 4 + 0] * linv, rv.y + acc[nt][i][q * 4 + 1] * linv,
                     rv.z + acc[nt][i][q * 4 + 2] * linv, rv.w + acc[nt][i][q * 4 + 3] * linv };
        *(float4*)(out + idx) = o;
      }
}

extern "C" void kernel_launch(void* const* d_in, const int* in_sizes, int n_in,
                              void* d_out, int out_size, void* d_ws, size_t ws_size,
                              hipStream_t stream) {
  const float* feature = (const float*)d_in[0];
  const float* wq = (const float*)d_in[1];
  const float* bq = (const float*)d_in[2];
  const float* wk = (const float*)d_in[3];
  const float* bk = (const float*)d_in[4];
  const float* wv = (const float*)d_in[5];
  const float* bv = (const float*)d_in[6];
  float* out = (float*)d_out;

  const size_t MN = (size_t)16384 * 512;
  short* Xb = (short*)d_ws;       // MN
  short* Wb = Xb + MN;            // 3 * 262144
  short* Q = Wb + 786432;         // MN (K follows contiguously)
  short* K = Q + MN;
  short* Vt = K + MN;             // [8][512][2048]
  short* P = Vt + MN;             // [8][2048][2048] unnormalized exp
  float* biasP = (float*)(P + (size_t)8 * 2048 * 2048);  // [3][512]
  float* l = biasP + 1536;        // [8*2048] row sums of exp

  prep<<<8968, 256, 0, stream>>>(feature, wq, wk, wv, bq, bk, bv, Xb, Wb, biasP, l);

  gemm_qkv<<<dim3(4, 128, 3), 256, 0, stream>>>(Xb, Wb, biasP, Q, Vt);
  gemm_qk<<<dim3(16, 16, 8), 256, 0, stream>>>(Q, K, P, l);

  const float iscl = 0.044194173824159216f;  // 1/sqrt(512)
  gemm_pv<<<dim3(2, 32, 8), 256, 0, stream>>>(P, Vt, l, feature, out, iscl);
}

// Round 10
// 251.214 us; speedup vs baseline: 1.0414x; 1.0414x over previous
//
#include <hip/hip_runtime.h>
#include <cstdint>
#include <cstddef>

// B=8, N=2048, C=512
// out = feature + softmax(Q K^T) @ V / sqrt(C),  Q = X Wq^T + bq etc.
// R10: gemm_qkv reverted to R8's 16x16x32 form (R9's 32x32 there raised
//      VGPR 88->124 + 3.1e6 bank conflicts -> 62.9 µs). QK/PV keep R9's
//      32x32x16 (both verified <=62.5 µs). BK=64 XOR-swizzled LDS
//      (0 conflicts in 16x16 pattern, proven R6/R8).

typedef __bf16 bf16x8 __attribute__((ext_vector_type(8)));
typedef float f32x4 __attribute__((ext_vector_type(4)));
typedef float f32x16 __attribute__((ext_vector_type(16)));
typedef short short4v __attribute__((ext_vector_type(4)));
typedef short short8v __attribute__((ext_vector_type(8)));

__device__ __forceinline__ short f2b(float f) {
  union { float f; unsigned u; } u; u.f = f;
  unsigned r = (u.u + 0x7fffu + ((u.u >> 16) & 1u)) >> 16;  // RNE
  return (short)r;
}

#define GLDS(gptr, lptr) \
  __builtin_amdgcn_global_load_lds( \
      (const __attribute__((address_space(1))) unsigned int*)(const void*)(gptr), \
      (__attribute__((address_space(3))) unsigned int*)(void*)(lptr), 16, 0, 0)

// fragment load from a row-major [rows][64] LDS buffer with XOR-swizzled
// 8-short chunks. kq = chunk index before swizzle.
__device__ __forceinline__ bf16x8 ldfrag64(const short* buf, int row, int kq) {
  return *(const bf16x8*)(buf + row * 64 + ((kq ^ (row & 7)) * 8));
}

// ---------------- merged prep: feature->bf16, weights->bf16, bias pack, l=0 ----------------
__global__ __launch_bounds__(256) void prep(const float* __restrict__ f,
                                            const float* __restrict__ w0,
                                            const float* __restrict__ w1,
                                            const float* __restrict__ w2,
                                            const float* __restrict__ b0,
                                            const float* __restrict__ b1,
                                            const float* __restrict__ b2,
                                            short* __restrict__ Xb, short* __restrict__ Wb,
                                            float* __restrict__ biasP, float* __restrict__ l) {
  const int bid = blockIdx.x;
  const int t = threadIdx.x;
  if (bid < 8192) {                       // feature: 2097152 float4
    int i = bid * 256 + t;
    float4 v = ((const float4*)f)[i];
    short4v o = { f2b(v.x), f2b(v.y), f2b(v.z), f2b(v.w) };
    *(short4v*)(Xb + (size_t)i * 4) = o;
  } else if (bid < 8960) {                // weights: 196608 float4
    int i = (bid - 8192) * 256 + t;
    const float* src = (i < 65536) ? w0 : (i < 131072) ? w1 : w2;
    float4 v = ((const float4*)src)[i & 65535];
    short4v o = { f2b(v.x), f2b(v.y), f2b(v.z), f2b(v.w) };
    *(short4v*)(Wb + (size_t)i * 4) = o;
  } else {                                // 8 blocks: l zero (16384 f32) + bias (1536)
    int i = (bid - 8960) * 256 + t;       // 0..2047
    float4 z = { 0.f, 0.f, 0.f, 0.f };
    ((float4*)l)[i * 2] = z;
    ((float4*)l)[i * 2 + 1] = z;
    if (i < 1536) {
      const float* s = (i < 512) ? b0 : (i < 1024) ? b1 : b2;
      biasP[i] = s[i & 511];
    }
  }
}

// ---------------- fused QKV projection: 128x128 tile, BK=64 swizzled, 16x16x32 ----------------
// z<2 (Q,K): A-op = W rows -> n-contiguous quads -> store [m][n].
// z==2 (V):  A-op = X rows -> m-contiguous quads -> store Vt[d][m] directly.
__global__ __launch_bounds__(256) void gemm_qkv(const short* __restrict__ X,
                                                const short* __restrict__ Wall,
                                                const float* __restrict__ biasP,
                                                short* __restrict__ Out,
                                                short* __restrict__ VtOut) {
  __shared__ __align__(16) short Xs[128 * 64];
  __shared__ __align__(16) short Ws[128 * 64];
  const int z = blockIdx.z;
  const short* Wm = Wall + (size_t)z * 262144;
  const int m0 = blockIdx.y * 128, n0 = blockIdx.x * 128;
  const int t = threadIdx.x;
  const int lane = t & 63, w = t >> 6;
  const int wn = (w & 1) * 64, wm = (w >> 1) * 64;
  const int fr = lane & 15, l4 = lane >> 4;

  f32x4 acc[4][4] = {};

  for (int k0 = 0; k0 < 512; k0 += 64) {
    __syncthreads();
#pragma unroll
    for (int u = 0; u < 4; ++u) {
      int cc = t + u * 256;
      int r = cc >> 3, cs = cc & 7;
      int kk = ((cs ^ (r & 7)) * 8);
      GLDS(X + (size_t)(m0 + r) * 512 + k0 + kk, Xs + cc * 8);
      GLDS(Wm + (size_t)(n0 + r) * 512 + k0 + kk, Ws + cc * 8);
    }
    __syncthreads();
#pragma unroll
    for (int h = 0; h < 2; ++h) {
      bf16x8 wf[4], xf[4];
#pragma unroll
      for (int i = 0; i < 4; ++i) wf[i] = ldfrag64(Ws, wn + i * 16 + fr, h * 4 + l4);
#pragma unroll
      for (int j = 0; j < 4; ++j) xf[j] = ldfrag64(Xs, wm + j * 16 + fr, h * 4 + l4);
      if (z < 2) {
#pragma unroll
        for (int i = 0; i < 4; ++i)
#pragma unroll
          for (int j = 0; j < 4; ++j)
            acc[i][j] = __builtin_amdgcn_mfma_f32_16x16x32_bf16(wf[i], xf[j], acc[i][j], 0, 0, 0);
      } else {
#pragma unroll
        for (int i = 0; i < 4; ++i)
#pragma unroll
          for (int j = 0; j < 4; ++j)
            acc[i][j] = __builtin_amdgcn_mfma_f32_16x16x32_bf16(xf[i], wf[j], acc[i][j], 0, 0, 0);
      }
    }
  }

  const int rq = l4 * 4;
  if (z < 2) {
    // acc[i][j]: C-row = n (quad-contig), C-col = m
#pragma unroll
    for (int i = 0; i < 4; ++i) {
      int nb = n0 + wn + i * 16 + rq;
      float4 bs = *(const float4*)(biasP + z * 512 + nb);
#pragma unroll
      for (int j = 0; j < 4; ++j) {
        int m = m0 + wm + j * 16 + fr;
        short4v o = { f2b(acc[i][j][0] + bs.x), f2b(acc[i][j][1] + bs.y),
                      f2b(acc[i][j][2] + bs.z), f2b(acc[i][j][3] + bs.w) };
        *(short4v*)(Out + (size_t)z * 8388608 + (size_t)m * 512 + nb) = o;
      }
    }
  } else {
    // acc[i][j]: C-row = m (quad-contig), C-col = d -> Vt[batch][d][token]
    const int zB = blockIdx.y >> 4;          // 128-row tiles, 16 per batch
    const int mb = m0 & 2047;
#pragma unroll
    for (int j = 0; j < 4; ++j) {
      int d = n0 + wn + j * 16 + fr;
      float bd = biasP[1024 + d];
#pragma unroll
      for (int i = 0; i < 4; ++i) {
        int mloc = mb + wm + i * 16 + rq;
        short4v o = { f2b(acc[i][j][0] + bd), f2b(acc[i][j][1] + bd),
                      f2b(acc[i][j][2] + bd), f2b(acc[i][j][3] + bd) };
        *(short4v*)(VtOut + (size_t)zB * 1048576 + (size_t)d * 2048 + mloc) = o;
      }
    }
  }
}

// ---------------- QK^T: 128x128 tile, BK=64 swizzled, 32x32x16, exp epilogue ----------------
// grid (16, 16, 8) = 2048 blocks. A-op = K rows (key quad-contig), B-op = Q rows.
__global__ __launch_bounds__(256) void gemm_qk(const short* __restrict__ Q,
                                               const short* __restrict__ Kb,
                                               short* __restrict__ P,
                                               float* __restrict__ l) {
  __shared__ __align__(16) short Qs[128 * 64];
  __shared__ __align__(16) short Ks[128 * 64];
  const int z = blockIdx.z;
  const short* A = Q + (size_t)z * 2048 * 512;
  const short* Bm = Kb + (size_t)z * 2048 * 512;
  const int m0 = blockIdx.y * 128, n0 = blockIdx.x * 128;
  const int t = threadIdx.x;
  const int lane = t & 63, w = t >> 6;
  const int wn = (w & 1) * 64, wm = (w >> 1) * 64;
  const int c31 = lane & 31, l5 = lane >> 5;

  f32x16 acc[2][2] = {};  // [i over keys][j over queries]

  for (int k0 = 0; k0 < 512; k0 += 64) {
    __syncthreads();
#pragma unroll
    for (int u = 0; u < 4; ++u) {
      int cc = t + u * 256;
      int r = cc >> 3, cs = cc & 7;
      int kk = ((cs ^ (r & 7)) * 8);
      GLDS(A + (size_t)(m0 + r) * 512 + k0 + kk, Qs + cc * 8);
      GLDS(Bm + (size_t)(n0 + r) * 512 + k0 + kk, Ks + cc * 8);
    }
    __syncthreads();
#pragma unroll
    for (int ks = 0; ks < 4; ++ks) {
      const int kq = ks * 2 + l5;
      bf16x8 kf[2], qf[2];
#pragma unroll
      for (int i = 0; i < 2; ++i) kf[i] = ldfrag64(Ks, wn + i * 32 + c31, kq);
#pragma unroll
      for (int j = 0; j < 2; ++j) qf[j] = ldfrag64(Qs, wm + j * 32 + c31, kq);
#pragma unroll
      for (int i = 0; i < 2; ++i)
#pragma unroll
        for (int j = 0; j < 2; ++j)
          acc[i][j] = __builtin_amdgcn_mfma_f32_32x32x16_bf16(kf[i], qf[j], acc[i][j], 0, 0, 0);
    }
  }

  float rs[2] = { 0.f, 0.f };  // per query-subtile row sums (this lane's query col)
#pragma unroll
  for (int i = 0; i < 2; ++i)
#pragma unroll
    for (int q = 0; q < 4; ++q) {
      int nb = n0 + wn + i * 32 + q * 8 + l5 * 4;
#pragma unroll
      for (int j = 0; j < 2; ++j) {
        int m = m0 + wm + j * 32 + c31;
        short4v o;
        float part = 0.f;
#pragma unroll
        for (int r = 0; r < 4; ++r) {
          float e = exp2f(acc[i][j][q * 4 + r] * 1.4426950408889634f);
          o[r] = f2b(e);
          part += e;
        }
        *(short4v*)(P + (size_t)z * 4194304 + (size_t)m * 2048 + nb) = o;
        rs[j] += part;
      }
    }
  // lanes l and l^32 cover complementary key rows for the same query col
#pragma unroll
  for (int j = 0; j < 2; ++j) rs[j] += __shfl_xor(rs[j], 32);
  if (lane < 32) {
#pragma unroll
    for (int j = 0; j < 2; ++j)
      atomicAdd(&l[z * 2048 + m0 + wm + j * 32 + lane], rs[j]);
  }
}

// ---------------- PV: 64x256 per block (2 n-tiles share Ps), BK=64 swizzled, 32x32x16 ----------------
// grid (2, 32, 8). A-op = Vt rows (d quad-contig), B-op = P rows.
__global__ __launch_bounds__(256) void gemm_pv(const short* __restrict__ Pm,
                                               const short* __restrict__ Vt,
                                               const float* __restrict__ l,
                                               const float* __restrict__ resid,
                                               float* __restrict__ out, float scale) {
  __shared__ __align__(16) short Ps[64 * 64];        // 8 KB
  __shared__ __align__(16) short Vs[2][128 * 64];    // 32 KB
  const int z = blockIdx.z;
  const short* A = Pm + (size_t)z * 4194304;   // [2048][2048]
  const short* Bm = Vt + (size_t)z * 1048576;  // [512][2048]
  const int m0 = blockIdx.y * 64, n0 = blockIdx.x * 256;
  const int t = threadIdx.x;
  const int lane = t & 63, w = t >> 6;
  const int wn = (w & 1) * 64, wm = (w >> 1) * 32;
  const int c31 = lane & 31, l5 = lane >> 5;

  f32x16 acc[2][2] = {};  // [nt][i over d]; queries = wave's 32-row group

  for (int k0 = 0; k0 < 2048; k0 += 64) {
    __syncthreads();
#pragma unroll
    for (int u = 0; u < 2; ++u) {        // Ps: 512 chunks
      int cc = t + u * 256;
      int r = cc >> 3, cs = cc & 7;
      int kk = ((cs ^ (r & 7)) * 8);
      GLDS(A + (size_t)(m0 + r) * 2048 + k0 + kk, Ps + cc * 8);
    }
#pragma unroll
    for (int nt = 0; nt < 2; ++nt)
#pragma unroll
      for (int u = 0; u < 4; ++u) {      // Vs[nt]: 1024 chunks
        int cc = t + u * 256;
        int r = cc >> 3, cs = cc & 7;
        int kk = ((cs ^ (r & 7)) * 8);
        GLDS(Bm + (size_t)(n0 + nt * 128 + r) * 2048 + k0 + kk, Vs[nt] + cc * 8);
      }
    __syncthreads();
#pragma unroll
    for (int ks = 0; ks < 4; ++ks) {
      const int kq = ks * 2 + l5;
      bf16x8 pf = ldfrag64(Ps, wm + c31, kq);
#pragma unroll
      for (int nt = 0; nt < 2; ++nt)
#pragma unroll
        for (int i = 0; i < 2; ++i) {
          bf16x8 vf = ldfrag64(Vs[nt], wn + i * 32 + c31, kq);
          acc[nt][i] = __builtin_amdgcn_mfma_f32_32x32x16_bf16(vf, pf, acc[nt][i], 0, 0, 0);
        }
    }
  }

  const int m = m0 + wm + c31;
  const float linv = scale / l[z * 2048 + m];
#pragma unroll
  for (int nt = 0; nt < 2; ++nt)
#pragma unroll
    for (int i = 0; i < 2; ++i)
#pragma unroll
      for (int q = 0; q < 4; ++q) {
        int d = n0 + nt * 128 + wn + i * 32 + q * 8 + l5 * 4;
        size_t idx = (size_t)z * 1048576 + (size_t)m * 512 + d;
        float4 rv = *(const float4*)(resid + idx);
        float4 o = { rv.x + acc[nt][i][q * 4 + 0] * linv, rv.y + acc[nt][i][q * 4 + 1] * linv,
                     rv.z + acc[nt][i][q * 4 + 2] * linv, rv.w + acc[nt][i][q * 4 + 3] * linv };
        *(float4*)(out + idx) = o;
      }
}

extern "C" void kernel_launch(void* const* d_in, const int* in_sizes, int n_in,
                              void* d_out, int out_size, void* d_ws, size_t ws_size,
                              hipStream_t stream) {
  const float* feature = (const float*)d_in[0];
  const float* wq = (const float*)d_in[1];
  const float* bq = (const float*)d_in[2];
  const float* wk = (const float*)d_in[3];
  const float* bk = (const float*)d_in[4];
  const float* wv = (const float*)d_in[5];
  const float* bv = (const float*)d_in[6];
  float* out = (float*)d_out;

  const size_t MN = (size_t)16384 * 512;
  short* Xb = (short*)d_ws;       // MN
  short* Wb = Xb + MN;            // 3 * 262144
  short* Q = Wb + 786432;         // MN (K follows contiguously)
  short* K = Q + MN;
  short* Vt = K + MN;             // [8][512][2048]
  short* P = Vt + MN;             // [8][2048][2048] unnormalized exp
  float* biasP = (float*)(P + (size_t)8 * 2048 * 2048);  // [3][512]
  float* l = biasP + 1536;        // [8*2048] row sums of exp

  prep<<<8968, 256, 0, stream>>>(feature, wq, wk, wv, bq, bk, bv, Xb, Wb, biasP, l);

  gemm_qkv<<<dim3(4, 128, 3), 256, 0, stream>>>(Xb, Wb, biasP, Q, Vt);
  gemm_qk<<<dim3(16, 16, 8), 256, 0, stream>>>(Q, K, P, l);

  const float iscl = 0.044194173824159216f;  // 1/sqrt(512)
  gemm_pv<<<dim3(2, 32, 8), 256, 0, stream>>>(P, Vt, l, feature, out, iscl);
}